// Round 15
// baseline (815.266 us; speedup 1.0000x reference)
//
#include <hip/hip_runtime.h>
#include <math.h>

#define LL 2048
#define MM 12
#define DD 128
#define TP 256   // T
#define MEGA_LDS 78464

typedef short short8 __attribute__((ext_vector_type(8)));
typedef short short4v __attribute__((ext_vector_type(4)));
typedef float float4v __attribute__((ext_vector_type(4)));

static __device__ __forceinline__ unsigned short f2b(float f) {
  union { float f; unsigned int u; } x; x.f = f;
  unsigned int r = x.u + 0x7fffu + ((x.u >> 16) & 1u);
  return (unsigned short)(r >> 16);
}
static __device__ __forceinline__ float b2f(unsigned short u) {
  union { unsigned int u; float f; } x; x.u = ((unsigned int)u) << 16;
  return x.f;
}
static __device__ __forceinline__ float qxor1(float x) {
  int r = __builtin_amdgcn_mov_dpp(__builtin_bit_cast(int, x), 0xB1, 0xF, 0xF, true);
  return __builtin_bit_cast(float, r);
}
static __device__ __forceinline__ float qxor2(float x) {
  int r = __builtin_amdgcn_mov_dpp(__builtin_bit_cast(int, x), 0x4E, 0xF, 0xF, true);
  return __builtin_bit_cast(float, r);
}

// ---------------- convert weights to bf16 (pw, in_w, out_w, padded xp_w, padded ew) ----------------
__global__ __launch_bounds__(256) void k_cvt(const float* __restrict__ pw_w, const float* __restrict__ in_w,
                                             const float* __restrict__ out_w, const float* __restrict__ xp_w,
                                             const float* __restrict__ ew,
                                             unsigned short* __restrict__ pwbf) {
  int i = blockIdx.x * 256 + threadIdx.x;
  if (i < 49152) { pwbf[i] = f2b(pw_w[i]); return; }
  int i2 = i - 49152;
  if (i2 < 131072) { pwbf[i] = f2b(in_w[i2]); return; }
  int i3 = i2 - 131072;
  if (i3 < 65536) { pwbf[i] = f2b(out_w[i3]); return; }
  int i4 = i3 - 65536;
  if (i4 < 24576) {
    int layer = (i4 < 12288) ? 0 : 1;
    int rem = i4 - layer * 12288;
    int k = rem >> 8, c = rem & 255;
    float v = (k < 40) ? xp_w[layer * 10240 + k * 256 + c] : 0.0f;
    pwbf[i] = f2b(v);
    return;
  }
  int i5 = i4 - 24576;
  if (i5 < 4096) {
    int d = i5 >> 5, k = i5 & 31;
    float v = (k < 16) ? ew[d * 16 + k] : 0.0f;
    pwbf[i] = f2b(v);
  }
}

// ---------------- convert fc_w -> bf16 padded [32][32768] ----------------
__global__ __launch_bounds__(256) void k_cvt2(const float* __restrict__ fw, unsigned short* __restrict__ fwbf) {
  int i = blockIdx.x * 256 + threadIdx.x;
  int m = i >> 15, k = i & 32767;
  fwbf[i] = f2b((m < 18) ? fw[m * 32768 + k] : 0.0f);
}

// ---------------- embedding via MFMA ----------------
__global__ __launch_bounds__(256) void k_emb(const float* __restrict__ inp,
                                             const unsigned short* __restrict__ ewbf,
                                             const float* __restrict__ eb,
                                             unsigned short* __restrict__ xe) {
  int sig = blockIdx.x;
  int b = sig / MM, m = sig % MM;
  __shared__ float xs[LL];
  const float* ib = inp + (size_t)b * LL * MM + m;
  int tid = threadIdx.x;
  for (int i = tid; i < LL; i += 256) xs[i] = ib[(size_t)i * MM];
  __syncthreads();
  int wv = tid >> 6, ln = tid & 15, q = (tid >> 4) & 3;
  short8 af[8];
#pragma unroll
  for (int et = 0; et < 8; ++et)
    af[et] = *(const short8*)(ewbf + (et * 16 + ln) * 32 + q * 8);
#pragma unroll
  for (int pass = 0; pass < 4; ++pass) {
    int t = pass * 64 + wv * 16 + ln;
    int l0 = t * 8 - 4;
    short8 bfrag;
#pragma unroll
    for (int j = 0; j < 8; ++j) {
      int k = q * 8 + j;
      int l = l0 + k;
      float v = (k < 16 && l >= 0 && l < LL) ? xs[l] : 0.0f;
      bfrag[j] = (short)f2b(v);
    }
    float4v acc[8];
#pragma unroll
    for (int et = 0; et < 8; ++et) {
      acc[et] = (float4v){0.f, 0.f, 0.f, 0.f};
      acc[et] = __builtin_amdgcn_mfma_f32_16x16x32_bf16(af[et], bfrag, acc[et], 0, 0, 0);
    }
    unsigned short* orow = xe + (size_t)sig * 32768 + (size_t)t * 128;
#pragma unroll
    for (int et = 0; et < 8; ++et) {
      int e = et * 16 + q * 4;
      float4 pb = *(const float4*)&eb[e];
      short4v st = {(short)f2b(acc[et][0] + pb.x), (short)f2b(acc[et][1] + pb.y),
                    (short)f2b(acc[et][2] + pb.z), (short)f2b(acc[et][3] + pb.w)};
      *(short4v*)(orow + e) = st;
    }
  }
}

// ---------------- MEGA block stage (register-lean): all 3 layers + SE, signal resident in LDS ----------------
__global__ __launch_bounds__(512, 4) void k_mega(const unsigned short* __restrict__ u0,
                                                 const float* __restrict__ dww, const float* __restrict__ dwb,
                                                 const unsigned short* __restrict__ pwbf,
                                                 const float* __restrict__ pwb,
                                                 const float* __restrict__ w1, const float* __restrict__ b1,
                                                 const float* __restrict__ w2, const float* __restrict__ b2,
                                                 unsigned short* __restrict__ uout) {
  extern __shared__ char smemraw[];
  unsigned short* us = (unsigned short*)smemraw;
  float* dwT  = (float*)(smemraw + 69632);
  float* dwbL = dwT + 640;
  float* pwbL = dwbL + 128;
  float* sred = pwbL + 128;
  float* smv  = sred + 1024;
  float* hh   = smv + 128;
  float* aL   = hh + 32;

  int sig = blockIdx.x;
  int tid = threadIdx.x;
  const size_t gbase = (size_t)sig * 32768;
  int cu = tid & 15;
  int r0 = tid >> 4;

#pragma unroll
  for (int p = 0; p < 8; ++p) {
    int t = p * 32 + r0;
    short8 v = *(const short8*)(u0 + gbase + (size_t)t * 128 + cu * 8);
    *(short8*)(us + t * 136 + cu * 8) = v;
  }

  int wv = tid >> 6;
  int ln = tid & 15;
  int q  = (tid >> 4) & 3;
  int tb = wv * 32;

  for (int layer = 0; layer < 3; ++layer) {
    __syncthreads();
    for (int i = tid; i < 640; i += 512) dwT[(i % 5) * 128 + (i / 5)] = dww[layer * 640 + i];
    if (tid < 128) { dwbL[tid] = dwb[layer * 128 + tid]; pwbL[tid] = pwb[layer * 128 + tid]; }
    __syncthreads();

    const unsigned short* pwL = pwbf + layer * 16384;
    float4v acc[2][8];
#pragma unroll
    for (int tl = 0; tl < 2; ++tl)
#pragma unroll
      for (int et = 0; et < 8; ++et) acc[tl][et] = (float4v){0.f, 0.f, 0.f, 0.f};

#pragma unroll
    for (int kc = 0; kc < 4; ++kc) {
      int dc = kc * 32 + q * 8;
#pragma unroll
      for (int tl = 0; tl < 2; ++tl) {
        int t = tb + tl * 16 + ln;
        float a8[8];
        {
          float4 ba = *(const float4*)&dwbL[dc];
          float4 bb2 = *(const float4*)&dwbL[dc + 4];
          a8[0] = ba.x; a8[1] = ba.y; a8[2] = ba.z; a8[3] = ba.w;
          a8[4] = bb2.x; a8[5] = bb2.y; a8[6] = bb2.z; a8[7] = bb2.w;
        }
#pragma unroll
        for (int k = 0; k < 5; ++k) {
          int tt = t - 2 + k;
          if (tt >= 0 && tt < 256) {
            short8 u8 = *(const short8*)(us + tt * 136 + dc);
            float4 wa = *(const float4*)&dwT[k * 128 + dc];
            float4 wb = *(const float4*)&dwT[k * 128 + dc + 4];
            a8[0] += b2f((unsigned short)u8[0]) * wa.x;
            a8[1] += b2f((unsigned short)u8[1]) * wa.y;
            a8[2] += b2f((unsigned short)u8[2]) * wa.z;
            a8[3] += b2f((unsigned short)u8[3]) * wa.w;
            a8[4] += b2f((unsigned short)u8[4]) * wb.x;
            a8[5] += b2f((unsigned short)u8[5]) * wb.y;
            a8[6] += b2f((unsigned short)u8[6]) * wb.z;
            a8[7] += b2f((unsigned short)u8[7]) * wb.w;
          }
        }
        short8 bf;
#pragma unroll
        for (int j = 0; j < 8; ++j)
          bf[j] = (short)f2b(0.5f * a8[j] * (1.0f + erff(a8[j] * 0.70710678118654752f)));
#pragma unroll
        for (int et = 0; et < 8; ++et) {
          short8 af = *(const short8*)(pwL + (size_t)(et * 16 + ln) * 128 + dc);
          acc[tl][et] = __builtin_amdgcn_mfma_f32_16x16x32_bf16(af, bf, acc[tl][et], 0, 0, 0);
        }
      }
    }
    __syncthreads();   // all us reads done; sred free

    // SE t-partial sums -> sred
#pragma unroll
    for (int et = 0; et < 8; ++et) {
      int e = et * 16 + q * 4;
      float4 pb = *(const float4*)&pwbL[e];
      float sv0 = acc[0][et][0] + acc[1][et][0] + 2.0f * pb.x;
      float sv1 = acc[0][et][1] + acc[1][et][1] + 2.0f * pb.y;
      float sv2 = acc[0][et][2] + acc[1][et][2] + 2.0f * pb.z;
      float sv3 = acc[0][et][3] + acc[1][et][3] + 2.0f * pb.w;
#pragma unroll
      for (int m = 1; m <= 8; m <<= 1) {
        sv0 += __shfl_xor(sv0, m, 64);
        sv1 += __shfl_xor(sv1, m, 64);
        sv2 += __shfl_xor(sv2, m, 64);
        sv3 += __shfl_xor(sv3, m, 64);
      }
      if (ln == 0) {
        float4 sv = {sv0, sv1, sv2, sv3};
        *(float4*)&sred[wv * 128 + e] = sv;
      }
    }
    __syncthreads();
    if (tid < 128) {
      float s = 0.f;
#pragma unroll
      for (int w = 0; w < 8; ++w) s += sred[w * 128 + tid];
      smv[tid] = s * (1.0f / 256.0f);
    }
    __syncthreads();
    if (tid < 32) {
      float a1 = b1[layer * 32 + tid];
      for (int d = 0; d < 128; ++d) a1 += w1[layer * 4096 + tid * 128 + d] * smv[d];
      hh[tid] = fmaxf(a1, 0.0f);
    }
    __syncthreads();
    if (tid < 128) {
      float a2 = b2[layer * 128 + tid];
#pragma unroll
      for (int r = 0; r < 32; ++r) a2 += w2[layer * 4096 + tid * 32 + r] * hh[r];
      aL[tid] = 1.0f / (1.0f + expf(-a2));
    }
    __syncthreads();

    // u += w * a  (in LDS, disjoint per lane)
#pragma unroll
    for (int tl = 0; tl < 2; ++tl) {
      int t = tb + tl * 16 + ln;
#pragma unroll
      for (int et = 0; et < 8; ++et) {
        int e = et * 16 + q * 4;
        float4 pb = *(const float4*)&pwbL[e];
        float4 ga = *(const float4*)&aL[e];
        short4v u4 = *(short4v*)(us + t * 136 + e);
        short4v r;
        r[0] = (short)f2b(b2f((unsigned short)u4[0]) + (acc[tl][et][0] + pb.x) * ga.x);
        r[1] = (short)f2b(b2f((unsigned short)u4[1]) + (acc[tl][et][1] + pb.y) * ga.y);
        r[2] = (short)f2b(b2f((unsigned short)u4[2]) + (acc[tl][et][2] + pb.z) * ga.z);
        r[3] = (short)f2b(b2f((unsigned short)u4[3]) + (acc[tl][et][3] + pb.w) * ga.w);
        *(short4v*)(us + t * 136 + e) = r;
      }
    }
  }
  __syncthreads();
#pragma unroll
  for (int p = 0; p < 8; ++p) {
    int t = p * 32 + r0;
    short8 v = *(short8*)(us + t * 136 + cu * 8);
    *(short8*)(uout + gbase + (size_t)t * 128 + cu * 8) = v;
  }
}

// ---------------- mean over M -> xe2 fp32 + xe2bf bf16 ----------------
__global__ __launch_bounds__(256) void k_reduce2(const unsigned short* __restrict__ u,
                                                 float* __restrict__ xe2,
                                                 unsigned short* __restrict__ xe2bf) {
  int i = blockIdx.x * 256 + threadIdx.x;
  int d0 = (i & 15) * 8;
  int t = (i >> 4) & 255;
  int b = i >> 12;
  float acc[8] = {0.f, 0.f, 0.f, 0.f, 0.f, 0.f, 0.f, 0.f};
#pragma unroll 4
  for (int m = 0; m < 12; ++m) {
    size_t base = ((size_t)(b * 12 + m) * 256 + t) * 128 + d0;
    short8 u8 = *(const short8*)(u + base);
#pragma unroll
    for (int j = 0; j < 8; ++j) acc[j] += b2f((unsigned short)u8[j]);
  }
  size_t off = (size_t)b * 32768 + (size_t)t * 128 + d0;
  float4 o0 = {acc[0] / 12.f, acc[1] / 12.f, acc[2] / 12.f, acc[3] / 12.f};
  float4 o1 = {acc[4] / 12.f, acc[5] / 12.f, acc[6] / 12.f, acc[7] / 12.f};
  *(float4*)(xe2 + off) = o0;
  *(float4*)(xe2 + off + 4) = o1;
  short8 ob;
#pragma unroll
  for (int j = 0; j < 8; ++j) ob[j] = (short)f2b(acc[j] / 12.f);
  *(short8*)(xe2bf + off) = ob;
}

// ---------------- mamba: in-projection via MFMA, zero-LDS -> bf16 xz[t][e] ----------------
__global__ __launch_bounds__(256) void k_inproj(const unsigned short* __restrict__ xe2bf,
                                                const unsigned short* __restrict__ inwbf,
                                                unsigned short* __restrict__ xz) {
  int blk = blockIdx.x;
  int b = blk >> 3;
  int tt = (blk >> 1) & 3;
  int eh = blk & 1;
  int t0 = tt * 64, e0 = eh * 256;
  int tid = threadIdx.x;
  int wv = tid >> 6, ln = tid & 15, q = (tid >> 4) & 3;
  int t = t0 + wv * 16 + ln;
  const unsigned short* xrow = xe2bf + ((size_t)b * 256 + t) * 128 + q * 8;
  short8 bfrag[4];
#pragma unroll
  for (int kc = 0; kc < 4; ++kc) bfrag[kc] = *(const short8*)(xrow + kc * 32);
  float4v acc[16];
#pragma unroll
  for (int et = 0; et < 16; ++et) acc[et] = (float4v){0.f, 0.f, 0.f, 0.f};
#pragma unroll
  for (int et = 0; et < 16; ++et) {
    const unsigned short* arow = inwbf + (size_t)(e0 + et * 16 + ln) * 128 + q * 8;
#pragma unroll
    for (int kc = 0; kc < 4; ++kc) {
      short8 af = *(const short8*)(arow + kc * 32);
      acc[et] = __builtin_amdgcn_mfma_f32_16x16x32_bf16(af, bfrag[kc], acc[et], 0, 0, 0);
    }
  }
  unsigned short* orow = xz + ((size_t)b * 256 + t) * 512 + e0 + q * 4;
#pragma unroll
  for (int et = 0; et < 16; ++et) {
    short4v st = {(short)f2b(acc[et][0]), (short)f2b(acc[et][1]),
                  (short)f2b(acc[et][2]), (short)f2b(acc[et][3])};
    *(short4v*)(orow + et * 16) = st;
  }
}

// ---------------- mamba: fused causal conv+SiLU -> x-projection MFMA; writes xc + dbl ----------------
__global__ __launch_bounds__(256) void k_xproj(const unsigned short* __restrict__ xz,
                                               const float* __restrict__ cw, const float* __restrict__ cb,
                                               const unsigned short* __restrict__ xwbf,
                                               unsigned short* __restrict__ xcg,
                                               float* __restrict__ dbl) {
  __shared__ unsigned short xis[67 * 264];
  int blk = blockIdx.x;
  int b = blk >> 2;
  int tq = blk & 3;
  int t0 = tq * 64;
  int tid = threadIdx.x;

  const short8 ZV = {0, 0, 0, 0, 0, 0, 0, 0};
  for (int idx = tid; idx < 2144; idx += 256) {
    int row = idx >> 5, cu = idx & 31;
    int t = t0 - 3 + row;
    short8 v = ZV;
    if (t >= 0) v = *(const short8*)(xz + ((size_t)b * 256 + t) * 512 + cu * 8);
    *(short8*)(xis + row * 264 + cu * 8) = v;
  }
  __syncthreads();

  int cu = tid & 31;
  int rb = tid >> 5;
  int c8 = cu * 8;
  float wl[4][8], bl[8];
#pragma unroll
  for (int j = 0; j < 8; ++j) {
    float4 w4 = *(const float4*)&cw[(c8 + j) * 4];
    wl[0][j] = w4.x; wl[1][j] = w4.y; wl[2][j] = w4.z; wl[3][j] = w4.w;
    bl[j] = cb[c8 + j];
  }

  short8 vv[4];
#pragma unroll
  for (int s = 0; s < 4; ++s) {
    int r = rb + s * 8;
    float acc[8];
#pragma unroll
    for (int j = 0; j < 8; ++j) acc[j] = bl[j];
#pragma unroll
    for (int k = 0; k < 4; ++k) {
      short8 u8 = *(const short8*)(xis + (r + k) * 264 + c8);
#pragma unroll
      for (int j = 0; j < 8; ++j) acc[j] += b2f((unsigned short)u8[j]) * wl[k][j];
    }
#pragma unroll
    for (int j = 0; j < 8; ++j)
      vv[s][j] = (short)f2b(acc[j] / (1.0f + __expf(-acc[j])));
    *(short8*)(xcg + ((size_t)b * 256 + t0 + r) * 256 + c8) = vv[s];
  }
  __syncthreads();
#pragma unroll
  for (int s = 0; s < 4; ++s)
    *(short8*)(xis + (rb + s * 8) * 264 + c8) = vv[s];

#pragma unroll
  for (int s = 0; s < 4; ++s) {
    int r = 32 + rb + s * 8;
    float acc[8];
#pragma unroll
    for (int j = 0; j < 8; ++j) acc[j] = bl[j];
#pragma unroll
    for (int k = 0; k < 4; ++k) {
      short8 u8 = *(const short8*)(xis + (r + k) * 264 + c8);
#pragma unroll
      for (int j = 0; j < 8; ++j) acc[j] += b2f((unsigned short)u8[j]) * wl[k][j];
    }
#pragma unroll
    for (int j = 0; j < 8; ++j)
      vv[s][j] = (short)f2b(acc[j] / (1.0f + __expf(-acc[j])));
    *(short8*)(xcg + ((size_t)b * 256 + t0 + r) * 256 + c8) = vv[s];
  }
  __syncthreads();
#pragma unroll
  for (int s = 0; s < 4; ++s)
    *(short8*)(xis + (32 + rb + s * 8) * 264 + c8) = vv[s];
  __syncthreads();

  int wv = tid >> 6, ln = tid & 15, q = (tid >> 4) & 3;
  int tl = wv * 16 + ln;
  short8 bfrag[8];
#pragma unroll
  for (int kc = 0; kc < 8; ++kc)
    bfrag[kc] = *(const short8*)(xis + tl * 264 + kc * 32 + q * 8);
  float4v acc[3];
#pragma unroll
  for (int et = 0; et < 3; ++et) acc[et] = (float4v){0.f, 0.f, 0.f, 0.f};
#pragma unroll
  for (int et = 0; et < 3; ++et) {
    const unsigned short* arow = xwbf + (size_t)(et * 16 + ln) * 256 + q * 8;
#pragma unroll
    for (int kc = 0; kc < 8; ++kc) {
      short8 af = *(const short8*)(arow + kc * 32);
      acc[et] = __builtin_amdgcn_mfma_f32_16x16x32_bf16(af, bfrag[kc], acc[et], 0, 0, 0);
    }
  }
  float* drow = dbl + ((size_t)b * 256 + t0 + tl) * 40;
#pragma unroll
  for (int et = 0; et < 3; ++et)
#pragma unroll
    for (int r = 0; r < 4; ++r) {
      int k = et * 16 + q * 4 + r;
      if (k < 40) drow[k] = acc[et][r];
    }
}

// ---------------- mamba: fused dt + selective scan + y-finalize ----------------
__global__ __launch_bounds__(128) void k_scan2(const float* __restrict__ dbl,
                                               const unsigned short* __restrict__ xc,
                                               const unsigned short* __restrict__ xz,
                                               const float* __restrict__ Alog,
                                               const float* __restrict__ dtw, const float* __restrict__ dtbv,
                                               const float* __restrict__ Dp, unsigned short* __restrict__ y) {
  __shared__ float ds[32][40];
  __shared__ float dxs[32][32][4];
  __shared__ float yl[32][32];
  __shared__ float dtwL[32][8];
  __shared__ float dtbL[32];
  __shared__ float DpL[32];

  int b = blockIdx.x >> 3;
  int c0 = (blockIdx.x & 7) * 32;
  int tid = threadIdx.x;

  for (int idx = tid; idx < 256; idx += 128) dtwL[idx >> 3][idx & 7] = dtw[(c0 + (idx >> 3)) * 8 + (idx & 7)];
  if (tid < 32) { dtbL[tid] = dtbv[c0 + tid]; DpL[tid] = Dp[c0 + tid]; }

  int lane = tid & 63;
  int wv = tid >> 6;
  int c_loc = wv * 16 + (lane >> 2);
  int c = c0 + c_loc;
  int sblk = (lane & 3) * 4;

  float4 Al = *(const float4*)&Alog[c * 16 + sblk];
  float A[4] = {-__expf(Al.x), -__expf(Al.y), -__expf(Al.z), -__expf(Al.w)};
  float h[4] = {0.f, 0.f, 0.f, 0.f};

  const float* dbp = dbl + (size_t)b * 10240;
  const unsigned short* xcp = xc + (size_t)b * 65536;
  const unsigned short* xzp = xz + (size_t)b * 131072;
  unsigned short* yp = y + (size_t)b * 65536;

  for (int chk = 0; chk < 8; ++chk) {
    int t0c = chk * 32;
    for (int idx = tid; idx < 1280; idx += 128) ((float*)ds)[idx] = dbp[t0c * 40 + idx];
    for (int idx = tid; idx < 512; idx += 128) {
      int t = idx >> 4, cc2 = (idx & 15) * 2;
      ushort2 xv = *(const ushort2*)&xcp[(size_t)(t0c + t) * 256 + c0 + cc2];
      ushort2 zv = *(const ushort2*)&xzp[(size_t)(t0c + t) * 512 + 256 + c0 + cc2];
      dxs[t][cc2][1] = b2f(xv.x);
      dxs[t][cc2 + 1][1] = b2f(xv.y);
      dxs[t][cc2][2] = b2f(zv.x);
      dxs[t][cc2 + 1][2] = b2f(zv.y);
    }
    __syncthreads();
    for (int idx = tid; idx < 1024; idx += 128) {
      int t = idx >> 5, cc = idx & 31;
      const float* dr = ds[t];
      const float* wr = dtwL[cc];
      float acc = dtbL[cc];
#pragma unroll
      for (int j = 0; j < 8; ++j) acc += wr[j] * dr[j];
      dxs[t][cc][0] = (acc > 20.0f) ? acc : __logf(1.0f + __expf(acc));
    }
    __syncthreads();
#pragma unroll 4
    for (int t = 0; t < 32; ++t) {
      float4 dx = *(const float4*)&dxs[t][c_loc][0];
      float4 Bv = *(const float4*)&ds[t][8 + sblk];
      float4 Cv = *(const float4*)&ds[t][24 + sblk];
      float dtv = dx.x;
      float bx = dtv * dx.y;
      h[0] = __expf(dtv * A[0]) * h[0] + Bv.x * bx;
      h[1] = __expf(dtv * A[1]) * h[1] + Bv.y * bx;
      h[2] = __expf(dtv * A[2]) * h[2] + Bv.z * bx;
      h[3] = __expf(dtv * A[3]) * h[3] + Bv.w * bx;
      float p = h[0] * Cv.x;
      p = fmaf(h[1], Cv.y, p);
      p = fmaf(h[2], Cv.z, p);
      p = fmaf(h[3], Cv.w, p);
      p += qxor1(p);
      p += qxor2(p);
      if ((lane & 3) == 0) yl[t][c_loc] = p;
    }
    __syncthreads();
    for (int idx = tid; idx < 512; idx += 128) {
      int t = idx >> 4, cc2 = (idx & 15) * 2;
      float p0 = yl[t][cc2], p1 = yl[t][cc2 + 1];
      float x0 = dxs[t][cc2][1], x1 = dxs[t][cc2 + 1][1];
      float z0 = dxs[t][cc2][2], z1 = dxs[t][cc2 + 1][2];
      float s0 = z0 / (1.0f + __expf(-z0));
      float s1 = z1 / (1.0f + __expf(-z1));
      ushort2 o = {f2b((p0 + DpL[cc2] * x0) * s0), f2b((p1 + DpL[cc2 + 1] * x1) * s1)};
      *(ushort2*)&yp[(size_t)(t0c + t) * 256 + c0 + cc2] = o;
    }
    __syncthreads();
  }
}

// ---------------- mamba: MFMA out-projection + residual + LayerNorm, zero-LDS ----------------
__global__ __launch_bounds__(128) void k_outln(const unsigned short* __restrict__ yb,
                                               const unsigned short* __restrict__ owbf,
                                               float* __restrict__ xe2, unsigned short* __restrict__ xe2bf,
                                               const float* __restrict__ g, const float* __restrict__ bb) {
  int blk = blockIdx.x;
  int b = blk >> 3;
  int t0 = (blk & 7) * 32;
  int tid = threadIdx.x;
  int wv = tid >> 6, ln = tid & 15, q = (tid >> 4) & 3;
  int t = t0 + wv * 16 + ln;

  const unsigned short* yrow = yb + ((size_t)b * 256 + t) * 256 + q * 8;
  short8 bfrag[8];
#pragma unroll
  for (int kc = 0; kc < 8; ++kc) bfrag[kc] = *(const short8*)(yrow + kc * 32);

  float4v acc[8];
#pragma unroll
  for (int et = 0; et < 8; ++et) acc[et] = (float4v){0.f, 0.f, 0.f, 0.f};
#pragma unroll
  for (int et = 0; et < 8; ++et) {
    const unsigned short* arow = owbf + (size_t)(et * 16 + ln) * 256 + q * 8;
#pragma unroll
    for (int kc = 0; kc < 8; ++kc) {
      short8 af = *(const short8*)(arow + kc * 32);
      acc[et] = __builtin_amdgcn_mfma_f32_16x16x32_bf16(af, bfrag[kc], acc[et], 0, 0, 0);
    }
  }

  float* xrow = xe2 + ((size_t)b * 256 + t) * 128;
  float vals[8][4];
  float s1 = 0.f, s2 = 0.f;
#pragma unroll
  for (int et = 0; et < 8; ++et) {
    float4 res = *(const float4*)(xrow + et * 16 + q * 4);
    float rv[4] = {res.x, res.y, res.z, res.w};
#pragma unroll
    for (int r = 0; r < 4; ++r) {
      float v = acc[et][r] + rv[r];
      vals[et][r] = v;
      s1 += v;
      s2 += v * v;
    }
  }
  s1 += __shfl_xor(s1, 16, 64);
  s1 += __shfl_xor(s1, 32, 64);
  s2 += __shfl_xor(s2, 16, 64);
  s2 += __shfl_xor(s2, 32, 64);
  float mu = s1 * (1.0f / 128.0f);
  float rs = rsqrtf(s2 * (1.0f / 128.0f) - mu * mu + 1e-5f);

  unsigned short* brow = xe2bf + ((size_t)b * 256 + t) * 128;
#pragma unroll
  for (int et = 0; et < 8; ++et) {
    int d = et * 16 + q * 4;
    float4 g4 = *(const float4*)(g + d);
    float4 b4 = *(const float4*)(bb + d);
    float o0 = (vals[et][0] - mu) * rs * g4.x + b4.x;
    float o1 = (vals[et][1] - mu) * rs * g4.y + b4.y;
    float o2 = (vals[et][2] - mu) * rs * g4.z + b4.z;
    float o3 = (vals[et][3] - mu) * rs * g4.w + b4.w;
    float4 of = {o0, o1, o2, o3};
    *(float4*)(xrow + d) = of;
    short4v ob = {(short)f2b(o0), (short)f2b(o1), (short)f2b(o2), (short)f2b(o3)};
    *(short4v*)(brow + d) = ob;
  }
}

// ---------------- xflat transpose (+bf16 copy, + pred bias init) ----------------
__global__ __launch_bounds__(256) void k_xflat(const float* __restrict__ xe2, float* __restrict__ out,
                                               unsigned short* __restrict__ outbf,
                                               const float* __restrict__ fcb, float* __restrict__ pred) {
  int b = blockIdx.x >> 5;
  int blk = blockIdx.x & 31;
  int t0 = (blk >> 2) * 32, d0 = (blk & 3) * 32;
  __shared__ float tile[32][33];
  int tid = threadIdx.x;
  if (blockIdx.x == 0) {
    for (int i = tid; i < 1152; i += 256) pred[i] = fcb[i % 18];
  }
#pragma unroll
  for (int q = 0; q < 4; ++q) {
    int t = (tid >> 5) + q * 8, dd = tid & 31;
    tile[t][dd] = xe2[(size_t)b * 32768 + (size_t)(t0 + t) * 128 + d0 + dd];
  }
  __syncthreads();
#pragma unroll
  for (int q = 0; q < 4; ++q) {
    int dd = (tid >> 5) + q * 8, t = tid & 31;
    float v = tile[t][dd];
    size_t o = (size_t)b * 32768 + (size_t)(d0 + dd) * 256 + t0 + t;
    out[o] = v;
    outbf[o] = f2b(v);
  }
}

// ---------------- final FC via MFMA ----------------
__global__ __launch_bounds__(256) void k_fc(const unsigned short* __restrict__ xflatbf,
                                            const unsigned short* __restrict__ fwbf,
                                            float* __restrict__ pred) {
  int kb = blockIdx.x;
  int k0 = kb * 256;
  int tid = threadIdx.x;
  int wv = tid >> 6, ln = tid & 15, q = (tid >> 4) & 3;
  int b = wv * 16 + ln;
  const unsigned short* xrow = xflatbf + (size_t)b * 32768 + k0 + q * 8;
  float4v acc[2];
  acc[0] = (float4v){0.f, 0.f, 0.f, 0.f};
  acc[1] = (float4v){0.f, 0.f, 0.f, 0.f};
#pragma unroll
  for (int kc = 0; kc < 8; ++kc) {
    short8 bfrag = *(const short8*)(xrow + kc * 32);
#pragma unroll
    for (int et = 0; et < 2; ++et) {
      short8 af = *(const short8*)(fwbf + (size_t)(et * 16 + ln) * 32768 + k0 + kc * 32 + q * 8);
      acc[et] = __builtin_amdgcn_mfma_f32_16x16x32_bf16(af, bfrag, acc[et], 0, 0, 0);
    }
  }
#pragma unroll
  for (int et = 0; et < 2; ++et)
#pragma unroll
    for (int r = 0; r < 4; ++r) {
      int c = et * 16 + q * 4 + r;
      if (c < 18) atomicAdd(&pred[b * 18 + c], acc[et][r]);
    }
}

extern "C" void kernel_launch(void* const* d_in, const int* in_sizes, int n_in,
                              void* d_out, int out_size, void* d_ws, size_t ws_size,
                              hipStream_t stream) {
  (void)in_sizes; (void)n_in; (void)out_size; (void)ws_size;
  const float* inp    = (const float*)d_in[0];
  const float* emb_w  = (const float*)d_in[1];
  const float* emb_b  = (const float*)d_in[2];
  const float* dw_w   = (const float*)d_in[3];
  const float* dw_b   = (const float*)d_in[4];
  const float* pw_w   = (const float*)d_in[5];
  const float* pw_b   = (const float*)d_in[6];
  const float* se_w1  = (const float*)d_in[7];
  const float* se_b1  = (const float*)d_in[8];
  const float* se_w2  = (const float*)d_in[9];
  const float* se_b2  = (const float*)d_in[10];
  const float* in_w   = (const float*)d_in[11];
  const float* conv_w = (const float*)d_in[12];
  const float* conv_b = (const float*)d_in[13];
  const float* xp_w   = (const float*)d_in[14];
  const float* dt_w   = (const float*)d_in[15];
  const float* dt_b   = (const float*)d_in[16];
  const float* Alog   = (const float*)d_in[17];
  const float* Dp     = (const float*)d_in[18];
  const float* out_w  = (const float*)d_in[19];
  const float* ln_g   = (const float*)d_in[20];
  const float* ln_b   = (const float*)d_in[21];
  const float* fc_w   = (const float*)d_in[22];
  const float* fc_b   = (const float*)d_in[23];

  char* ws = (char*)d_ws;
  unsigned short* U0 = (unsigned short*)(ws);
  unsigned short* xz = (unsigned short*)(ws);
  unsigned short* xc = (unsigned short*)(ws + 33554432);
  unsigned short* yb = (unsigned short*)(ws + 50331648);
  float* xe2 = (float*)(ws + 100663296);
  unsigned short* xflatbf = (unsigned short*)(ws + 109051904);
  unsigned short* fwbf = (unsigned short*)(ws + 113246208);
  float* dbl = (float*)(ws + 150994944);
  unsigned short* xe2bf = (unsigned short*)(ws + 153616384);

  float* xflat = (float*)d_out;
  float* pred  = xflat + (size_t)64 * 32768;
  unsigned short* pwbf  = (unsigned short*)d_out;
  unsigned short* inwbf = pwbf + 49152;
  unsigned short* owbf  = inwbf + 131072;
  unsigned short* xwbf  = owbf + 65536;
  unsigned short* ewbf  = xwbf + 24576;

  hipFuncSetAttribute((const void*)k_mega, hipFuncAttributeMaxDynamicSharedMemorySize, MEGA_LDS);

  k_cvt<<<1072, 256, 0, stream>>>(pw_w, in_w, out_w, xp_w, emb_w, pwbf);
  k_emb<<<768, 256, 0, stream>>>(inp, ewbf, emb_b, U0);

  k_mega<<<768, 512, MEGA_LDS, stream>>>(U0, dw_w, dw_b, pwbf, pw_b,
                                         se_w1, se_b1, se_w2, se_b2, U0);

  k_reduce2<<<1024, 256, 0, stream>>>(U0, xe2, xe2bf);
  k_cvt2<<<4096, 256, 0, stream>>>(fc_w, fwbf);

  for (int i = 0; i < 2; ++i) {
    k_inproj<<<512, 256, 0, stream>>>(xe2bf, inwbf + i * 65536, xz);
    k_xproj<<<256, 256, 0, stream>>>(xz, conv_w + i * 1024, conv_b + i * 256,
                                     xwbf + i * 12288, xc, dbl);
    k_scan2<<<512, 128, 0, stream>>>(dbl, xc, xz, Alog + i * 4096,
                                     dt_w + i * 2048, dt_b + i * 256, Dp + i * 256, yb);
    k_outln<<<512, 128, 0, stream>>>(yb, owbf + i * 32768, xe2, xe2bf,
                                     ln_g + i * 128, ln_b + i * 128);
  }

  k_xflat<<<2048, 256, 0, stream>>>(xe2, xflat, xflatbf, fc_b, pred);
  k_fc<<<128, 256, 0, stream>>>(xflatbf, fwbf, pred);
}